// Round 6
// baseline (24580.347 us; speedup 1.0000x reference)
//
#include <hip/hip_runtime.h>

// TinyRNNPolicy: h_{t+1} = tanh(W h_t); action_t = tanh(mean(h_{t+1}[:2048]))
//
// R6: persistent kernel, 256 blocks x 512 threads (1 block/CU, 8 waves).
// KEY CHANGE vs R5: the per-step device barrier is GONE. h is exchanged as
// tagged 8-byte words: (uint32 tag = step+1) << 32 | fp32 bits. Consumers
// poll exactly the 8 h elements they will stage (2 producer blocks each) --
// the poll IS the data load, collapsing the old chain (h store -> vmcnt
// drain -> flag store -> flag poll -> h load) into one coherence-point hop.
// 2-buffer ping-pong is race-free without a barrier: writing h_{s+1} requires
// having read all of h_s, which requires all consumers finished h_{s-1}.
// W slice (128 floats/thread) pinned in AGPRs (R5 mechanism). LDS staging
// uses the mapping that measured ZERO bank conflicts in R2/R3/R5.

#define N 4096
#define HALF 2048
#define BLOCKS 256
#define TPB 512
#define RPB 16        // rows per block
#define CCOLS 128     // cols per thread-chunk
#define NCH 32        // chunks (4096/128)
#define PAD 132       // LDS chunk stride in floats (132%32==4)

// ws layout (dword offsets); ws re-poisoned 0xAA each launch -> init kernel.
// Poison tag 0xAAAAAAAA never equals any expected tag (0..n_steps) -> safe.
#define WS_FLAGS 0            // 256 flags, stride 16 dwords (post-loop barrier)
#define WS_HTA   4096         // tagged h ping: 4096 x u64 (8192 dwords)
#define WS_HTB   12288        // tagged h pong: 4096 x u64
#define WS_ACC   20480        // accum[out_size] (fallback path only)
#define WS_PART  24576        // parts[n_steps*128] (big path)

typedef float f32x16 __attribute__((ext_vector_type(16)));
typedef unsigned long long u64;

__device__ __forceinline__ float agent_ld(const float* p) {
    return __hip_atomic_load(p, __ATOMIC_RELAXED, __HIP_MEMORY_SCOPE_AGENT);
}
__device__ __forceinline__ void agent_st(float* p, float v) {
    __hip_atomic_store(p, v, __ATOMIC_RELAXED, __HIP_MEMORY_SCOPE_AGENT);
}
__device__ __forceinline__ unsigned agent_ldu(const unsigned* p) {
    return __hip_atomic_load(p, __ATOMIC_RELAXED, __HIP_MEMORY_SCOPE_AGENT);
}
__device__ __forceinline__ void agent_stu(unsigned* p, unsigned v) {
    __hip_atomic_store(p, v, __ATOMIC_RELAXED, __HIP_MEMORY_SCOPE_AGENT);
}
__device__ __forceinline__ u64 agent_ld64(const u64* p) {
    return __hip_atomic_load(p, __ATOMIC_RELAXED, __HIP_MEMORY_SCOPE_AGENT);
}
__device__ __forceinline__ void agent_st64(u64* p, u64 v) {
    __hip_atomic_store(p, v, __ATOMIC_RELAXED, __HIP_MEMORY_SCOPE_AGENT);
}

__device__ __forceinline__ u64 pack_h(float v, unsigned tag) {
    return ((u64)tag << 32) | (u64)__float_as_uint(v);
}
__device__ __forceinline__ float unpack_v(u64 p) {
    return __uint_as_float((unsigned)(p & 0xffffffffull));
}
__device__ __forceinline__ unsigned unpack_t(u64 p) { return (unsigned)(p >> 32); }

__device__ __forceinline__ float tanh_fast(float x) {
    x = fminf(fmaxf(x, -15.0f), 15.0f);   // clamp avoids inf/inf
    float e = __expf(2.0f * x);
    return (e - 1.0f) / (e + 1.0f);       // exact 0 at x==0
}

__global__ void rnn_init(const float* __restrict__ h0, float* __restrict__ ws, int n_out) {
    int i = blockIdx.x * blockDim.x + threadIdx.x;
    if (i < BLOCKS * 16) agent_stu((unsigned*)ws + WS_FLAGS + i, 0u);
    if (i < n_out) agent_st(ws + WS_ACC + i, 0.0f);
    if (i < N) agent_st64((u64*)(ws + WS_HTA) + i, pack_h(h0[i], 0u));  // tag 0 = h_0
}

__global__ void __launch_bounds__(TPB, 2)
rnn_persistent(const float* __restrict__ W, const int* __restrict__ pns,
               float* __restrict__ out, float* __restrict__ ws, int big) {
    const int b = blockIdx.x;
    const int t = threadIdx.x;
    const int lane = t & 63;
    const int wave = t >> 6;       // 0..7
    const int row = t & 15;        // row within block's 16 rows
    const int chunk = t >> 4;      // 0..31, 128-col chunk
    const int grow = b * RPB + row;

    // ---- one-time: W slice (128 floats/thread) -> AGPR-class vectors ----
    f32x16 wa[8];
    {
        const float4* Wv = (const float4*)(W + (size_t)grow * N + (size_t)chunk * CCOLS);
#pragma unroll
        for (int i = 0; i < 8; ++i) {
#pragma unroll
            for (int q = 0; q < 4; ++q) {
                float4 v = Wv[i * 4 + q];
                wa[i][4*q+0] = v.x; wa[i][4*q+1] = v.y;
                wa[i][4*q+2] = v.z; wa[i][4*q+3] = v.w;
            }
        }
    }

    const int n_steps = *pns;

    __shared__ float hs[NCH * PAD];   // padded h broadcast (~16.5 KiB)
    __shared__ float part[128];       // 8 waves x 16 rows

    unsigned* flags = (unsigned*)ws + WS_FLAGS;
    u64* hTA   = (u64*)(ws + WS_HTA);
    u64* hTB   = (u64*)(ws + WS_HTB);
    float* accum = ws + WS_ACC;
    float* parts = ws + WS_PART;

    // this thread's two poll groups: elems [4t,4t+4) and [2048+4t, +4)
    const int e0 = 4 * t;
    const int e1 = 2048 + 4 * t;

    for (int s = 0; s < n_steps; ++s) {
        // pin W into AGPRs each iteration (home class AGPR, no competitors)
#pragma unroll
        for (int i = 0; i < 8; ++i) asm volatile("" : "+a"(wa[i]));

        const u64* src = (s & 1) ? hTB : hTA;
        u64*       dst = (s & 1) ? hTA : hTB;
        const unsigned etag = (unsigned)s;      // h_s carries tag s

        // ---- poll+load this thread's 8 tagged h words (1 coherence hop) ----
        u64 a0, a1, a2, a3, b0, b1, b2, b3;
        {
            unsigned spins = 0;
            for (;;) {
                a0 = agent_ld64(src + e0 + 0);
                a1 = agent_ld64(src + e0 + 1);
                a2 = agent_ld64(src + e0 + 2);
                a3 = agent_ld64(src + e0 + 3);
                b0 = agent_ld64(src + e1 + 0);
                b1 = agent_ld64(src + e1 + 1);
                b2 = agent_ld64(src + e1 + 2);
                b3 = agent_ld64(src + e1 + 3);
                bool ok = (unpack_t(a0) == etag) & (unpack_t(a1) == etag) &
                          (unpack_t(a2) == etag) & (unpack_t(a3) == etag) &
                          (unpack_t(b0) == etag) & (unpack_t(b1) == etag) &
                          (unpack_t(b2) == etag) & (unpack_t(b3) == etag);
                if (ok) break;
                __builtin_amdgcn_s_sleep(1);
                if (++spins > (1u << 20)) break;   // fail loud, don't hang
            }
        }

        // ---- stage to LDS: two float4 writes, zero-conflict mapping ----
        {
            int base0 = (t >> 5) * PAD + 4 * (t & 31);              // idx = t
            *(float4*)&hs[base0] = make_float4(unpack_v(a0), unpack_v(a1),
                                               unpack_v(a2), unpack_v(a3));
            int idx1 = t + TPB;                                     // idx = t+512
            int base1 = (idx1 >> 5) * PAD + 4 * (idx1 & 31);
            *(float4*)&hs[base1] = make_float4(unpack_v(b0), unpack_v(b1),
                                               unpack_v(b2), unpack_v(b3));
        }
        __syncthreads();

        // ---- 128 FMAs over this thread's chunk; W sourced from AGPRs ----
        float s0 = 0.f, s1 = 0.f, s2 = 0.f, s3 = 0.f;
        const int hb = chunk * PAD;
#pragma unroll
        for (int k = 0; k < CCOLS; k += 4) {
            float4 hv = *(const float4*)&hs[hb + k];
            s0 = fmaf(wa[k >> 4][(k & 15) + 0], hv.x, s0);
            s1 = fmaf(wa[k >> 4][(k & 15) + 1], hv.y, s1);
            s2 = fmaf(wa[k >> 4][(k & 15) + 2], hv.z, s2);
            s3 = fmaf(wa[k >> 4][(k & 15) + 3], hv.w, s3);
        }
        float v = (s0 + s1) + (s2 + s3);

        // ---- intra-wave reduce: wave's 4 chunks -> lanes 0..15 (16 rows) ----
        v += __shfl_down(v, 32);
        v += __shfl_down(v, 16);
        if (lane < 16) part[wave * 16 + lane] = v;
        __syncthreads();

        // ---- wave 0: final reduce, tanh, publish tagged h (data IS flag) ----
        if (wave == 0) {
            float hval = 0.0f;
            if (t < RPB) {
                float acc = 0.0f;
#pragma unroll
                for (int c = 0; c < TPB / 64; ++c) acc += part[c * 16 + t];
                hval = tanh_fast(acc);
                agent_st64(dst + b * RPB + t, pack_h(hval, (unsigned)(s + 1)));
            }
            // readout partial: sum of this block's 16 h values
            float r = (t < RPB) ? hval : 0.0f;
            r += __shfl_down(r, 8);
            r += __shfl_down(r, 4);
            r += __shfl_down(r, 2);
            r += __shfl_down(r, 1);
            if (t == 0 && b < (BLOCKS / 2)) {
                if (big) agent_st(parts + (size_t)s * 128 + b, r);
                else     atomicAdd(accum + s, r);
            }
        }

        // ---- fallback (!big) keeps a per-step flag barrier for out[s] ----
        if (!big) {
            __syncthreads();
            if (wave == 0) {
                asm volatile("s_waitcnt vmcnt(0)" ::: "memory");
                if (t == 0) agent_stu(flags + b * 16, (unsigned)(s + 1));
            }
            if (t < BLOCKS) {
                unsigned spins = 0;
                while (agent_ldu(flags + t * 16) < (unsigned)(s + 1)) {
                    __builtin_amdgcn_s_sleep(1);
                    if (++spins > (1u << 20)) break;
                }
            }
            __syncthreads();
            if (b == 0 && t == 0)
                out[s] = tanh_fast(agent_ld(accum + s) * (1.0f / (float)HALF));
        }
        // big path: NO per-step barrier; next iteration's poll enforces order.
    }

    // ---- big path: one final barrier, then all outputs in parallel ----
    if (big) {
        __syncthreads();
        if (wave == 0) {
            asm volatile("s_waitcnt vmcnt(0)" ::: "memory");
            if (t == 0) agent_stu(flags + b * 16, (unsigned)(n_steps + 1));
        }
        if (t < BLOCKS) {
            unsigned spins = 0;
            while (agent_ldu(flags + t * 16) < (unsigned)(n_steps + 1)) {
                __builtin_amdgcn_s_sleep(1);
                if (++spins > (1u << 20)) break;
            }
        }
        __syncthreads();

        const int l = t & 63;
        for (int ss = b * 8 + (t >> 6); ss < n_steps; ss += BLOCKS * 8) {
            float v = agent_ld(parts + (size_t)ss * 128 + l)
                    + agent_ld(parts + (size_t)ss * 128 + 64 + l);
            v += __shfl_down(v, 32);
            v += __shfl_down(v, 16);
            v += __shfl_down(v, 8);
            v += __shfl_down(v, 4);
            v += __shfl_down(v, 2);
            v += __shfl_down(v, 1);
            if (l == 0) out[ss] = tanh_fast(v * (1.0f / (float)HALF));
        }
    }
}

extern "C" void kernel_launch(void* const* d_in, const int* in_sizes, int n_in,
                              void* d_out, int out_size, void* d_ws, size_t ws_size,
                              hipStream_t stream) {
    const float* W  = (const float*)d_in[0];
    const float* h0 = (const float*)d_in[1];
    const int*  pns = (const int*)d_in[2];
    float* out = (float*)d_out;
    float* ws  = (float*)d_ws;

    size_t need = ((size_t)WS_PART + (size_t)out_size * 128) * 4;
    int big = (ws_size >= need) ? 1 : 0;

    int n_init = out_size > N ? out_size : N;
    rnn_init<<<(n_init + 255) / 256, 256, 0, stream>>>(h0, ws, out_size);
    rnn_persistent<<<BLOCKS, TPB, 0, stream>>>(W, pns, out, ws, big);
}